// Round 1
// baseline (1974.329 us; speedup 1.0000x reference)
//
#include <hip/hip_runtime.h>
#include <hip/hip_bf16.h>
#include <stdint.h>

// Problem constants
#define BB 16
#define NN 1620
#define DD 64
#define CC 128
#define KK 32
#define EPSV 1e-5f
#define PAIRS (BB*NN)            // 25920 (b,n) pairs
#define ROWS  (PAIRS*KK)         // 829440 rows of nf
#define TILES (ROWS/64)          // 12960 tiles of 64 rows (= 2 pairs)
#define TPB_TILES 8
#define GRID_MM (TILES/TPB_TILES) // 1620

// ---------------- transpose x (B,D,N) -> feats (B,N,D) ----------------
__global__ void __launch_bounds__(256) k_transpose_x(const float* __restrict__ x,
                                                     float* __restrict__ feats) {
    __shared__ float t[64*65];
    int b = blockIdx.y;
    int n0 = blockIdx.x * 64;
    int tid = threadIdx.x;
#pragma unroll
    for (int i = 0; i < 16; ++i) {
        int idx = i*256 + tid;
        int d = idx >> 6, nl = idx & 63;
        int n = n0 + nl;
        float v = 0.f;
        if (n < NN) v = x[((size_t)b*DD + d)*NN + n];
        t[d*65 + nl] = v;
    }
    __syncthreads();
#pragma unroll
    for (int i = 0; i < 16; ++i) {
        int idx = i*256 + tid;
        int nl = idx >> 6, d = idx & 63;
        int n = n0 + nl;
        if (n < NN) feats[((size_t)b*NN + n)*DD + d] = t[d*65 + nl];
    }
}

// ---------------- transpose w: wt[c][o] = w[o][c] ----------------
__global__ void k_transpose_w(const float* __restrict__ w1, const float* __restrict__ w2,
                              float* __restrict__ w1t, float* __restrict__ w2t) {
    int c = blockIdx.x, o = threadIdx.x;
    const float* w = blockIdx.y ? w2 : w1;
    float* wt = blockIdx.y ? w2t : w1t;
    wt[c*CC + o] = w[o*CC + c];
}

// ---------------- KNN: one wave per query ----------------
__global__ void __launch_bounds__(64) k_knn(const float* __restrict__ coords,
                                            int* __restrict__ idx_out) {
#pragma clang fp contract(off)
    __shared__ float dist[NN];
    int p = blockIdx.x;               // b*NN + n
    int b = p / NN, n = p - b*NN;
    int lane = threadIdx.x;
    const float* cb = coords + (size_t)b*NN*3;
    float qx = cb[n*3+0], qy = cb[n*3+1], qz = cb[n*3+2];
    float sqn = (qx*qx + qy*qy) + qz*qz;
    for (int m = lane; m < NN; m += 64) {
        float cx = cb[m*3+0], cy = cb[m*3+1], cz = cb[m*3+2];
        float sqm = (cx*cx + cy*cy) + cz*cz;
        float dot = (qx*cx + qy*cy) + qz*cz;
        dist[m] = (sqn + sqm) - 2.0f*dot;
    }
    __syncthreads();
    for (int k = 0; k < KK; ++k) {
        unsigned long long best = ~0ull;
        for (int m = lane; m < NN; m += 64) {
            float d = dist[m];
            unsigned u = __float_as_uint(d);
            u = (u & 0x80000000u) ? ~u : (u | 0x80000000u);
            unsigned long long key = ((unsigned long long)u << 32) | (unsigned)m;
            if (key < best) best = key;
        }
#pragma unroll
        for (int off = 32; off; off >>= 1) {
            unsigned long long o = __shfl_xor(best, off, 64);
            if (o < best) best = o;
        }
        int msel = (int)(unsigned)(best & 0xffffffffu);
        if (lane == 0) {
            idx_out[p*KK + k] = msel;
            dist[msel] = __int_as_float(0x7f800000);  // +inf
        }
        __syncthreads();
    }
}

// ---------------- mm1 + stats1 (z1 discarded) ----------------
__global__ void __launch_bounds__(256) k_mm1_stats(const float* __restrict__ feats,
                                                   const int* __restrict__ knn_idx,
                                                   const float* __restrict__ w1t,
                                                   float* __restrict__ gsum,
                                                   float* __restrict__ gsumsq) {
    __shared__ float nf[64*132];
    __shared__ int rowbase[64];
    __shared__ int ctrbase[64];
    int tid = threadIdx.x;
    int og = tid & 31, rg = tid >> 5;
    int o0 = og*4;
    float s[4]  = {0,0,0,0};
    float s2[4] = {0,0,0,0};

    for (int it = 0; it < TPB_TILES; ++it) {
        int tile = blockIdx.x * TPB_TILES + it;
        if (tid < 64) {
            int r = tid;
            int p = tile*2 + (r >> 5);
            int k = r & 31;
            int b = p / NN;
            int nb = knn_idx[p*KK + k];
            rowbase[r] = (b*NN + nb)*DD;
            ctrbase[r] = p*DD;
        }
        __syncthreads();
#pragma unroll
        for (int i = 0; i < 32; ++i) {
            int idx = i*256 + tid;       // 64 rows x 128 c
            int r = idx >> 7, c = idx & 127;
            float v;
            if (c < DD) v = feats[rowbase[r] + c] - feats[ctrbase[r] + c];
            else        v = feats[ctrbase[r] + (c - DD)];
            nf[r*132 + c] = v;
        }
        __syncthreads();

        float acc[8][4];
#pragma unroll
        for (int j = 0; j < 8; ++j)
#pragma unroll
            for (int oi = 0; oi < 4; ++oi) acc[j][oi] = 0.f;

        for (int c4 = 0; c4 < 32; ++c4) {
            int c = c4*4;
            float4 w0 = *(const float4*)&w1t[(c+0)*CC + o0];
            float4 w1_ = *(const float4*)&w1t[(c+1)*CC + o0];
            float4 w2_ = *(const float4*)&w1t[(c+2)*CC + o0];
            float4 w3_ = *(const float4*)&w1t[(c+3)*CC + o0];
#pragma unroll
            for (int j = 0; j < 8; ++j) {
                float4 a = *(const float4*)&nf[(rg*8 + j)*132 + c];
                acc[j][0] = fmaf(a.x, w0.x, fmaf(a.y, w1_.x, fmaf(a.z, w2_.x, fmaf(a.w, w3_.x, acc[j][0]))));
                acc[j][1] = fmaf(a.x, w0.y, fmaf(a.y, w1_.y, fmaf(a.z, w2_.y, fmaf(a.w, w3_.y, acc[j][1]))));
                acc[j][2] = fmaf(a.x, w0.z, fmaf(a.y, w1_.z, fmaf(a.z, w2_.z, fmaf(a.w, w3_.z, acc[j][2]))));
                acc[j][3] = fmaf(a.x, w0.w, fmaf(a.y, w1_.w, fmaf(a.z, w2_.w, fmaf(a.w, w3_.w, acc[j][3]))));
            }
        }
#pragma unroll
        for (int j = 0; j < 8; ++j)
#pragma unroll
            for (int oi = 0; oi < 4; ++oi) {
                float v = acc[j][oi];
                s[oi]  += v;
                s2[oi] += v*v;
            }
        __syncthreads();
    }
    // block reduce -> atomics
    float* red = nf;
#pragma unroll
    for (int oi = 0; oi < 4; ++oi) red[rg*CC + o0 + oi] = s[oi];
    __syncthreads();
    if (tid < CC) {
        float tot = 0.f;
#pragma unroll
        for (int r = 0; r < 8; ++r) tot += red[r*CC + tid];
        atomicAdd(&gsum[tid], tot);
    }
    __syncthreads();
#pragma unroll
    for (int oi = 0; oi < 4; ++oi) red[rg*CC + o0 + oi] = s2[oi];
    __syncthreads();
    if (tid < CC) {
        float tot = 0.f;
#pragma unroll
        for (int r = 0; r < 8; ++r) tot += red[r*CC + tid];
        atomicAdd(&gsumsq[tid], tot);
    }
}

// ---------------- finalize bn params: a = g*rsqrt(var+eps), c = b - mean*a ----------------
__global__ void k_finalize(const float* __restrict__ gsum, const float* __restrict__ gsumsq,
                           const float* __restrict__ g, const float* __restrict__ bb,
                           float* __restrict__ ab) {
    int o = threadIdx.x;
    float cnt = (float)ROWS;
    float mean = gsum[o] / cnt;
    float var = gsumsq[o] / cnt - mean*mean;
    float a = g[o] * rsqrtf(var + EPSV);
    ab[o] = a;
    ab[CC + o] = bb[o] - mean*a;
}

// ---------------- mm1 + bn1relu + mm2 + stats2 + k-max/min ----------------
__global__ void __launch_bounds__(256) k_mm2_fused(const float* __restrict__ feats,
                                                   const int* __restrict__ knn_idx,
                                                   const float* __restrict__ w1t,
                                                   const float* __restrict__ w2t,
                                                   const float* __restrict__ ab1,
                                                   float* __restrict__ gsum2,
                                                   float* __restrict__ gsumsq2,
                                                   float* __restrict__ wsmax,
                                                   float* __restrict__ wsmin) {
    __shared__ float nf[64*132];
    __shared__ int rowbase[64];
    __shared__ int ctrbase[64];
    int tid = threadIdx.x;
    int og = tid & 31, rg = tid >> 5;
    int o0 = og*4;
    float a1o[4], c1o[4];
#pragma unroll
    for (int oi = 0; oi < 4; ++oi) { a1o[oi] = ab1[o0 + oi]; c1o[oi] = ab1[CC + o0 + oi]; }
    float s[4]  = {0,0,0,0};
    float s2[4] = {0,0,0,0};

    for (int it = 0; it < TPB_TILES; ++it) {
        int tile = blockIdx.x * TPB_TILES + it;
        if (tid < 64) {
            int r = tid;
            int p = tile*2 + (r >> 5);
            int k = r & 31;
            int b = p / NN;
            int nb = knn_idx[p*KK + k];
            rowbase[r] = (b*NN + nb)*DD;
            ctrbase[r] = p*DD;
        }
        __syncthreads();
#pragma unroll
        for (int i = 0; i < 32; ++i) {
            int idx = i*256 + tid;
            int r = idx >> 7, c = idx & 127;
            float v;
            if (c < DD) v = feats[rowbase[r] + c] - feats[ctrbase[r] + c];
            else        v = feats[ctrbase[r] + (c - DD)];
            nf[r*132 + c] = v;
        }
        __syncthreads();

        float acc[8][4];
#pragma unroll
        for (int j = 0; j < 8; ++j)
#pragma unroll
            for (int oi = 0; oi < 4; ++oi) acc[j][oi] = 0.f;

        for (int c4 = 0; c4 < 32; ++c4) {
            int c = c4*4;
            float4 w0 = *(const float4*)&w1t[(c+0)*CC + o0];
            float4 w1_ = *(const float4*)&w1t[(c+1)*CC + o0];
            float4 w2_ = *(const float4*)&w1t[(c+2)*CC + o0];
            float4 w3_ = *(const float4*)&w1t[(c+3)*CC + o0];
#pragma unroll
            for (int j = 0; j < 8; ++j) {
                float4 a = *(const float4*)&nf[(rg*8 + j)*132 + c];
                acc[j][0] = fmaf(a.x, w0.x, fmaf(a.y, w1_.x, fmaf(a.z, w2_.x, fmaf(a.w, w3_.x, acc[j][0]))));
                acc[j][1] = fmaf(a.x, w0.y, fmaf(a.y, w1_.y, fmaf(a.z, w2_.y, fmaf(a.w, w3_.y, acc[j][1]))));
                acc[j][2] = fmaf(a.x, w0.z, fmaf(a.y, w1_.z, fmaf(a.z, w2_.z, fmaf(a.w, w3_.z, acc[j][2]))));
                acc[j][3] = fmaf(a.x, w0.w, fmaf(a.y, w1_.w, fmaf(a.z, w2_.w, fmaf(a.w, w3_.w, acc[j][3]))));
            }
        }
        __syncthreads();   // mm1 reads of nf complete
        // y1 = relu(a1*z1 + c1), write into LDS (overwrite nf)
#pragma unroll
        for (int j = 0; j < 8; ++j) {
            float4 yv;
            yv.x = fmaf(a1o[0], acc[j][0], c1o[0]); yv.x = yv.x > 0.f ? yv.x : 0.f;
            yv.y = fmaf(a1o[1], acc[j][1], c1o[1]); yv.y = yv.y > 0.f ? yv.y : 0.f;
            yv.z = fmaf(a1o[2], acc[j][2], c1o[2]); yv.z = yv.z > 0.f ? yv.z : 0.f;
            yv.w = fmaf(a1o[3], acc[j][3], c1o[3]); yv.w = yv.w > 0.f ? yv.w : 0.f;
            *(float4*)&nf[(rg*8 + j)*132 + o0] = yv;
        }
        __syncthreads();

        // mm2: z2 = y1 @ w2^T
#pragma unroll
        for (int j = 0; j < 8; ++j)
#pragma unroll
            for (int oi = 0; oi < 4; ++oi) acc[j][oi] = 0.f;

        for (int c4 = 0; c4 < 32; ++c4) {
            int c = c4*4;
            float4 w0 = *(const float4*)&w2t[(c+0)*CC + o0];
            float4 w1_ = *(const float4*)&w2t[(c+1)*CC + o0];
            float4 w2_ = *(const float4*)&w2t[(c+2)*CC + o0];
            float4 w3_ = *(const float4*)&w2t[(c+3)*CC + o0];
#pragma unroll
            for (int j = 0; j < 8; ++j) {
                float4 a = *(const float4*)&nf[(rg*8 + j)*132 + c];
                acc[j][0] = fmaf(a.x, w0.x, fmaf(a.y, w1_.x, fmaf(a.z, w2_.x, fmaf(a.w, w3_.x, acc[j][0]))));
                acc[j][1] = fmaf(a.x, w0.y, fmaf(a.y, w1_.y, fmaf(a.z, w2_.y, fmaf(a.w, w3_.y, acc[j][1]))));
                acc[j][2] = fmaf(a.x, w0.z, fmaf(a.y, w1_.z, fmaf(a.z, w2_.z, fmaf(a.w, w3_.z, acc[j][2]))));
                acc[j][3] = fmaf(a.x, w0.w, fmaf(a.y, w1_.w, fmaf(a.z, w2_.w, fmaf(a.w, w3_.w, acc[j][3]))));
            }
        }

        float mx[4], mn[4];
#pragma unroll
        for (int oi = 0; oi < 4; ++oi) { mx[oi] = -3.402823e38f; mn[oi] = 3.402823e38f; }
#pragma unroll
        for (int j = 0; j < 8; ++j)
#pragma unroll
            for (int oi = 0; oi < 4; ++oi) {
                float v = acc[j][oi];
                s[oi]  += v;
                s2[oi] += v*v;
                mx[oi] = v > mx[oi] ? v : mx[oi];
                mn[oi] = v < mn[oi] ? v : mn[oi];
            }
        __syncthreads();   // mm2 reads of nf complete
        float* redmx = nf;
        float* redmn = nf + 8*CC;
#pragma unroll
        for (int oi = 0; oi < 4; ++oi) {
            redmx[rg*CC + o0 + oi] = mx[oi];
            redmn[rg*CC + o0 + oi] = mn[oi];
        }
        __syncthreads();
        {
            int g = tid >> 7, o = tid & 127;   // 2 groups x 128 channels
            int rb = g*4;
            float M = redmx[(rb+0)*CC + o];
            float m_ = redmn[(rb+0)*CC + o];
#pragma unroll
            for (int r = 1; r < 4; ++r) {
                float v1 = redmx[(rb+r)*CC + o];
                float v2 = redmn[(rb+r)*CC + o];
                M  = v1 > M  ? v1 : M;
                m_ = v2 < m_ ? v2 : m_;
            }
            int p = tile*2 + g;
            wsmax[(size_t)p*CC + o] = M;
            wsmin[(size_t)p*CC + o] = m_;
        }
        __syncthreads();
    }
    // stats2 block reduce -> atomics
    float* red = nf;
#pragma unroll
    for (int oi = 0; oi < 4; ++oi) red[rg*CC + o0 + oi] = s[oi];
    __syncthreads();
    if (tid < CC) {
        float tot = 0.f;
#pragma unroll
        for (int r = 0; r < 8; ++r) tot += red[r*CC + tid];
        atomicAdd(&gsum2[tid], tot);
    }
    __syncthreads();
#pragma unroll
    for (int oi = 0; oi < 4; ++oi) red[rg*CC + o0 + oi] = s2[oi];
    __syncthreads();
    if (tid < CC) {
        float tot = 0.f;
#pragma unroll
        for (int r = 0; r < 8; ++r) tot += red[r*CC + tid];
        atomicAdd(&gsumsq2[tid], tot);
    }
}

// ---------------- epilogue: bn2+relu on max (or min if a<0), transpose to (B,C,N) ----------------
__global__ void __launch_bounds__(256) k_epilogue(const float* __restrict__ wsmax,
                                                  const float* __restrict__ wsmin,
                                                  const float* __restrict__ ab2,
                                                  float* __restrict__ out) {
    __shared__ float t[128*65];
    int b = blockIdx.y;
    int n0 = blockIdx.x * 64;
    int tid = threadIdx.x;
#pragma unroll
    for (int i = 0; i < 32; ++i) {
        int idx = i*256 + tid;        // 64 n x 128 o, lanes along o
        int nl = idx >> 7, o = idx & 127;
        int n = n0 + nl;
        float v = 0.f;
        if (n < NN) {
            float a = ab2[o], cc = ab2[CC + o];
            size_t p = (size_t)b*NN + n;
            float z = (a >= 0.f) ? wsmax[p*CC + o] : wsmin[p*CC + o];
            v = fmaf(a, z, cc);
            v = v > 0.f ? v : 0.f;
        }
        t[o*65 + nl] = v;
    }
    __syncthreads();
#pragma unroll
    for (int i = 0; i < 32; ++i) {
        int idx = i*256 + tid;        // 128 o x 64 n, lanes along n
        int o = idx >> 6, nl = idx & 63;
        int n = n0 + nl;
        if (n < NN) out[((size_t)b*CC + o)*NN + n] = t[o*65 + nl];
    }
}

extern "C" void kernel_launch(void* const* d_in, const int* in_sizes, int n_in,
                              void* d_out, int out_size, void* d_ws, size_t ws_size,
                              hipStream_t stream) {
    const float* x      = (const float*)d_in[0];
    const float* coords = (const float*)d_in[1];
    const float* w1     = (const float*)d_in[2];
    const float* g1     = (const float*)d_in[3];
    const float* b1     = (const float*)d_in[4];
    const float* w2     = (const float*)d_in[5];
    const float* g2     = (const float*)d_in[6];
    const float* b2     = (const float*)d_in[7];
    float* out = (float*)d_out;

    char* ws = (char*)d_ws;
    size_t off = 0;
    int* knn_idx = (int*)(ws + off);  off += (size_t)ROWS * sizeof(int);       // 3.32 MB
    float* stats = (float*)(ws + off); off += 1024 * sizeof(float);
    float* gsum1 = stats,       *gsq1 = stats + 128;
    float* gsum2 = stats + 256, *gsq2 = stats + 384;
    float* ab1   = stats + 512;  // a[128], c[128]
    float* ab2   = stats + 768;
    float* feats = (float*)(ws + off); off += (size_t)BB*NN*DD * sizeof(float); // 6.64 MB
    float* w1t   = (float*)(ws + off); off += CC*CC * sizeof(float);
    float* w2t   = (float*)(ws + off); off += CC*CC * sizeof(float);
    float* wsmax = (float*)(ws + off); off += (size_t)PAIRS*CC * sizeof(float); // 13.3 MB
    float* wsmin = (float*)(ws + off); off += (size_t)PAIRS*CC * sizeof(float); // 13.3 MB
    (void)ws_size; (void)in_sizes; (void)n_in; (void)out_size;

    hipMemsetAsync(stats, 0, 512 * sizeof(float), stream);

    dim3 gT((NN + 63)/64, BB);
    k_transpose_x<<<gT, 256, 0, stream>>>(x, feats);
    dim3 gW(CC, 2);
    k_transpose_w<<<gW, CC, 0, stream>>>(w1, w2, w1t, w2t);
    k_knn<<<PAIRS, 64, 0, stream>>>(coords, knn_idx);
    k_mm1_stats<<<GRID_MM, 256, 0, stream>>>(feats, knn_idx, w1t, gsum1, gsq1);
    k_finalize<<<1, CC, 0, stream>>>(gsum1, gsq1, g1, b1, ab1);
    k_mm2_fused<<<GRID_MM, 256, 0, stream>>>(feats, knn_idx, w1t, w2t, ab1,
                                             gsum2, gsq2, wsmax, wsmin);
    k_finalize<<<1, CC, 0, stream>>>(gsum2, gsq2, g2, b2, ab2);
    dim3 gE((NN + 63)/64, BB);
    k_epilogue<<<gE, 256, 0, stream>>>(wsmax, wsmin, ab2, out);
}

// Round 2
// 897.531 us; speedup vs baseline: 2.1997x; 2.1997x over previous
//
#include <hip/hip_runtime.h>
#include <hip/hip_fp16.h>
#include <stdint.h>

#define BB 16
#define NN 1620
#define DD 64
#define CC 128
#define KK 32
#define EPSV 1e-5f
#define PAIRS (BB*NN)            // 25920
#define ROWS  (PAIRS*KK)         // 829440
#define TILES (PAIRS/2)          // 12960 tiles of 64 rows
#define TPB_TILES 8
#define GRID_MM (TILES/TPB_TILES) // 1620

typedef _Float16 half8 __attribute__((ext_vector_type(8)));
typedef float f32x4 __attribute__((ext_vector_type(4)));

__device__ __forceinline__ float relu_(float v){ return v > 0.f ? v : 0.f; }

union H2U { __half2 h; unsigned u; };

// ---------------- x (B,D,N) fp32 -> feats (B,N,D) fp16 ----------------
__global__ void __launch_bounds__(256) k_prep_feats(const float* __restrict__ x,
                                                    __half* __restrict__ feats) {
    __shared__ float t[64*65];
    int b = blockIdx.y;
    int n0 = blockIdx.x * 64;
    int tid = threadIdx.x;
#pragma unroll
    for (int i = 0; i < 16; ++i) {
        int idx = i*256 + tid;
        int d = idx >> 6, nl = idx & 63;
        int n = n0 + nl;
        float v = 0.f;
        if (n < NN) v = x[((size_t)b*DD + d)*NN + n];
        t[d*65 + nl] = v;
    }
    __syncthreads();
#pragma unroll
    for (int i = 0; i < 8; ++i) {
        int idx = i*256 + tid;            // 64 nl x 32 d-pairs
        int nl = idx >> 5, dp = idx & 31;
        int n = n0 + nl;
        if (n < NN) {
            __half2 h = __floats2half2_rn(t[(dp*2)*65 + nl], t[(dp*2+1)*65 + nl]);
            *(__half2*)(feats + ((size_t)b*NN + n)*DD + dp*2) = h;
        }
    }
}

// ---------------- w fp32 -> fp16 (same [o][c] layout) ----------------
__global__ void k_convert_w(const float* __restrict__ w1, const float* __restrict__ w2,
                            __half* __restrict__ w1h, __half* __restrict__ w2h) {
    int i = blockIdx.x*256 + threadIdx.x;   // 64 blocks * 256 = 16384
    w1h[i] = __float2half(w1[i]);
    w2h[i] = __float2half(w2[i]);
}

// ---------------- KNN: one wave per query (unchanged, passed R1) ----------------
__global__ void __launch_bounds__(64) k_knn(const float* __restrict__ coords,
                                            int* __restrict__ idx_out) {
#pragma clang fp contract(off)
    __shared__ float dist[NN];
    int p = blockIdx.x;
    int b = p / NN, n = p - b*NN;
    int lane = threadIdx.x;
    const float* cb = coords + (size_t)b*NN*3;
    float qx = cb[n*3+0], qy = cb[n*3+1], qz = cb[n*3+2];
    float sqn = (qx*qx + qy*qy) + qz*qz;
    for (int m = lane; m < NN; m += 64) {
        float cx = cb[m*3+0], cy = cb[m*3+1], cz = cb[m*3+2];
        float sqm = (cx*cx + cy*cy) + cz*cz;
        float dot = (qx*cx + qy*cy) + qz*cz;
        dist[m] = (sqn + sqm) - 2.0f*dot;
    }
    __syncthreads();
    for (int k = 0; k < KK; ++k) {
        unsigned long long best = ~0ull;
        for (int m = lane; m < NN; m += 64) {
            float d = dist[m];
            unsigned u = __float_as_uint(d);
            u = (u & 0x80000000u) ? ~u : (u | 0x80000000u);
            unsigned long long key = ((unsigned long long)u << 32) | (unsigned)m;
            if (key < best) best = key;
        }
#pragma unroll
        for (int off = 32; off; off >>= 1) {
            unsigned long long o = __shfl_xor(best, off, 64);
            if (o < best) best = o;
        }
        int msel = (int)(unsigned)(best & 0xffffffffu);
        if (lane == 0) {
            idx_out[p*KK + k] = msel;
            dist[msel] = __int_as_float(0x7f800000);
        }
        __syncthreads();
    }
}

// Stage one 64-row nf tile into LDS in MFMA B-fragment chunk order.
// Chunk C (0..1023): rbk=C>>8, t=(C>>6)&3, q=(C>>4)&3, m=C&15
// holds nf[row=rbk*16+m][k=t*32+q*8 .. +7] as 8 fp16 (16B).
__device__ __forceinline__ void stage_tile(const __half* __restrict__ feats,
                                           const int* __restrict__ knn_idx,
                                           int tile, int tid,
                                           __half* nf, int* rowb, int* ctrb) {
    if (tid < 64) {
        int r = tid;
        int p = tile*2 + (r >> 5);
        int nb = knn_idx[p*KK + (r & 31)];
        int b = p / NN;
        rowb[r] = (b*NN + nb)*DD;
        ctrb[r] = p*DD;
    }
    __syncthreads();
#pragma unroll
    for (int i = 0; i < 4; ++i) {
        int C = i*256 + tid;
        int rr = ((C >> 8) << 4) | (C & 15);
        int k  = (((C >> 6) & 3) << 5) | (((C >> 4) & 3) << 3);
        union { uint4 u; __half2 h[4]; } A, Cc, R;
        if (k < DD) {
            A.u  = *(const uint4*)(feats + rowb[rr] + k);
            Cc.u = *(const uint4*)(feats + ctrb[rr] + k);
#pragma unroll
            for (int j = 0; j < 4; ++j) R.h[j] = __hsub2(A.h[j], Cc.h[j]);
        } else {
            R.u = *(const uint4*)(feats + ctrb[rr] + (k - DD));
        }
        *(uint4*)(nf + C*8) = R.u;
    }
}

// ---------------- pass 1: mm1 (MFMA) + stats1 ----------------
__global__ void __launch_bounds__(256) k_mm1_mfma(const __half* __restrict__ feats,
                                                  const int* __restrict__ knn_idx,
                                                  const __half* __restrict__ w1h,
                                                  float* __restrict__ gsum,
                                                  float* __restrict__ gsumsq) {
    __shared__ __align__(16) char smem[16384 + 512];
    __half* nf = (__half*)smem;
    int* rowb = (int*)(smem + 16384);
    int* ctrb = (int*)(smem + 16384 + 256);
    int tid = threadIdx.x;
    int lane = tid & 63, wid = tid >> 6;
    int m = lane & 15, q = lane >> 4;

    half8 w1f[2][4];
#pragma unroll
    for (int ob = 0; ob < 2; ++ob)
#pragma unroll
        for (int t = 0; t < 4; ++t)
            w1f[ob][t] = *(const half8*)(w1h + (wid*32 + ob*16 + m)*CC + t*32 + q*8);

    f32x4 zero4 = {0.f, 0.f, 0.f, 0.f};
    f32x4 ssum[2] = {zero4, zero4}, ssq[2] = {zero4, zero4};

    for (int it = 0; it < TPB_TILES; ++it) {
        int tile = blockIdx.x * TPB_TILES + it;
        stage_tile(feats, knn_idx, tile, tid, nf, rowb, ctrb);
        __syncthreads();

        f32x4 acc[2][4];
#pragma unroll
        for (int ob = 0; ob < 2; ++ob)
#pragma unroll
            for (int rbk = 0; rbk < 4; ++rbk) acc[ob][rbk] = zero4;

#pragma unroll
        for (int t = 0; t < 4; ++t)
#pragma unroll
            for (int rbk = 0; rbk < 4; ++rbk) {
                half8 bfr = *(const half8*)(nf + ((rbk*4 + t)*64 + lane)*8);
                acc[0][rbk] = __builtin_amdgcn_mfma_f32_16x16x32_f16(w1f[0][t], bfr, acc[0][rbk], 0, 0, 0);
                acc[1][rbk] = __builtin_amdgcn_mfma_f32_16x16x32_f16(w1f[1][t], bfr, acc[1][rbk], 0, 0, 0);
            }
#pragma unroll
        for (int ob = 0; ob < 2; ++ob)
#pragma unroll
            for (int rbk = 0; rbk < 4; ++rbk) {
                ssum[ob] += acc[ob][rbk];
                ssq[ob]  += acc[ob][rbk]*acc[ob][rbk];
            }
        __syncthreads();
    }
#pragma unroll
    for (int ob = 0; ob < 2; ++ob)
#pragma unroll
        for (int c = 0; c < 4; ++c) {
            float v = ssum[ob][c], v2 = ssq[ob][c];
#pragma unroll
            for (int off = 1; off < 16; off <<= 1) {
                v  += __shfl_xor(v,  off);
                v2 += __shfl_xor(v2, off);
            }
            if (m == 0) {
                int o = wid*32 + ob*16 + q*4 + c;
                atomicAdd(&gsum[o], v);
                atomicAdd(&gsumsq[o], v2);
            }
        }
}

// ---------------- finalize bn params ----------------
__global__ void k_finalize(const float* __restrict__ gsum, const float* __restrict__ gsumsq,
                           const float* __restrict__ g, const float* __restrict__ bb,
                           float* __restrict__ ab) {
    int o = threadIdx.x;
    float cnt = (float)ROWS;
    float mean = gsum[o] / cnt;
    float var = gsumsq[o] / cnt - mean*mean;
    float a = g[o] * rsqrtf(var + EPSV);
    ab[o] = a;
    ab[CC + o] = bb[o] - mean*a;
}

// ---------------- pass 2: mm1 + bn1relu + mm2 + stats2 + per-pair max/min ----------------
__global__ void __launch_bounds__(256) k_fused_mfma(const __half* __restrict__ feats,
                                                    const int* __restrict__ knn_idx,
                                                    const __half* __restrict__ w1h,
                                                    const __half* __restrict__ w2h,
                                                    const float* __restrict__ ab1,
                                                    float* __restrict__ gsum2,
                                                    float* __restrict__ gsumsq2,
                                                    float* __restrict__ wsmax,
                                                    float* __restrict__ wsmin) {
    __shared__ __align__(16) char smem[34304];
    __half* nf   = (__half*)smem;             // 16384 B chunk-order nf
    __half* y1s  = (__half*)(smem + 16384);   // 16384 B swizzled row-major y1
    float* redmx = (float*)smem;              // 32*132*4 = 16896 B (aliases nf/y1s)
    float* redmn = (float*)(smem + 16896);    // 16896 B
    int* rowb = (int*)(smem + 33792);
    int* ctrb = (int*)(smem + 34048);
    int tid = threadIdx.x;
    int lane = tid & 63, wid = tid >> 6;
    int m = lane & 15, q = lane >> 4;

    half8 w1f[2][4], w2f[2][4];
#pragma unroll
    for (int ob = 0; ob < 2; ++ob)
#pragma unroll
        for (int t = 0; t < 4; ++t) {
            int o = wid*32 + ob*16 + m;
            w1f[ob][t] = *(const half8*)(w1h + o*CC + t*32 + q*8);
            w2f[ob][t] = *(const half8*)(w2h + o*CC + t*32 + q*8);
        }
    f32x4 a1v[2], c1v[2];
#pragma unroll
    for (int ob = 0; ob < 2; ++ob) {
        a1v[ob] = *(const f32x4*)(ab1 + wid*32 + ob*16 + q*4);
        c1v[ob] = *(const f32x4*)(ab1 + CC + wid*32 + ob*16 + q*4);
    }
    f32x4 zero4 = {0.f, 0.f, 0.f, 0.f};
    f32x4 ssum[2] = {zero4, zero4}, ssq[2] = {zero4, zero4};

    for (int it = 0; it < TPB_TILES; ++it) {
        int tile = blockIdx.x * TPB_TILES + it;
        stage_tile(feats, knn_idx, tile, tid, nf, rowb, ctrb);
        __syncthreads();

        f32x4 acc[2][4];
#pragma unroll
        for (int ob = 0; ob < 2; ++ob)
#pragma unroll
            for (int rbk = 0; rbk < 4; ++rbk) acc[ob][rbk] = zero4;

        // mm1: z1^T = w1 . nf^T
#pragma unroll
        for (int t = 0; t < 4; ++t)
#pragma unroll
            for (int rbk = 0; rbk < 4; ++rbk) {
                half8 bfr = *(const half8*)(nf + ((rbk*4 + t)*64 + lane)*8);
                acc[0][rbk] = __builtin_amdgcn_mfma_f32_16x16x32_f16(w1f[0][t], bfr, acc[0][rbk], 0, 0, 0);
                acc[1][rbk] = __builtin_amdgcn_mfma_f32_16x16x32_f16(w1f[1][t], bfr, acc[1][rbk], 0, 0, 0);
            }
        // bn1 + relu, write y1 (swizzled chunks: ch' = ch ^ (row&15))
#pragma unroll
        for (int ob = 0; ob < 2; ++ob)
#pragma unroll
            for (int rbk = 0; rbk < 4; ++rbk) {
                f32x4 z = acc[ob][rbk];
                float y0 = relu_(fmaf(a1v[ob][0], z[0], c1v[ob][0]));
                float y1 = relu_(fmaf(a1v[ob][1], z[1], c1v[ob][1]));
                float y2 = relu_(fmaf(a1v[ob][2], z[2], c1v[ob][2]));
                float y3 = relu_(fmaf(a1v[ob][3], z[3], c1v[ob][3]));
                H2U p0, p1;
                p0.h = __floats2half2_rn(y0, y1);
                p1.h = __floats2half2_rn(y2, y3);
                int row = rbk*16 + m;
                int ch = (wid*4 + ob*2 + (q >> 1)) ^ m;
                uint2 v; v.x = p0.u; v.y = p1.u;
                *(uint2*)(y1s + row*CC + ch*8 + (q & 1)*4) = v;
            }
        __syncthreads();

        // mm2: z2^T = w2 . y1^T
#pragma unroll
        for (int ob = 0; ob < 2; ++ob)
#pragma unroll
            for (int rbk = 0; rbk < 4; ++rbk) acc[ob][rbk] = zero4;
#pragma unroll
        for (int t = 0; t < 4; ++t)
#pragma unroll
            for (int rbk = 0; rbk < 4; ++rbk) {
                int row = rbk*16 + m;
                int ch = (t*4 + q) ^ m;
                half8 bfr = *(const half8*)(y1s + row*CC + ch*8);
                acc[0][rbk] = __builtin_amdgcn_mfma_f32_16x16x32_f16(w2f[0][t], bfr, acc[0][rbk], 0, 0, 0);
                acc[1][rbk] = __builtin_amdgcn_mfma_f32_16x16x32_f16(w2f[1][t], bfr, acc[1][rbk], 0, 0, 0);
            }
#pragma unroll
        for (int ob = 0; ob < 2; ++ob)
#pragma unroll
            for (int rbk = 0; rbk < 4; ++rbk) {
                ssum[ob] += acc[ob][rbk];
                ssq[ob]  += acc[ob][rbk]*acc[ob][rbk];
            }
        __syncthreads();   // all y1 reads done before aliasing smem as redbuf

#pragma unroll
        for (int ob = 0; ob < 2; ++ob)
#pragma unroll
            for (int pr = 0; pr < 2; ++pr) {
                f32x4 a0 = acc[ob][pr*2], a1 = acc[ob][pr*2 + 1];
                f32x4 vmx, vmn;
#pragma unroll
                for (int c = 0; c < 4; ++c) {
                    vmx[c] = fmaxf(a0[c], a1[c]);
                    vmn[c] = fminf(a0[c], a1[c]);
                }
                int o0 = wid*32 + ob*16 + q*4;
                *(f32x4*)(redmx + (pr*16 + m)*132 + o0) = vmx;
                *(f32x4*)(redmn + (pr*16 + m)*132 + o0) = vmn;
            }
        __syncthreads();
        {
            int pr = tid >> 7, o = tid & 127;
            float M  = redmx[(pr*16)*132 + o];
            float Mn = redmn[(pr*16)*132 + o];
#pragma unroll
            for (int mm = 1; mm < 16; ++mm) {
                M  = fmaxf(M,  redmx[(pr*16 + mm)*132 + o]);
                Mn = fminf(Mn, redmn[(pr*16 + mm)*132 + o]);
            }
            int p = tile*2 + pr;
            wsmax[(size_t)p*CC + o] = M;
            wsmin[(size_t)p*CC + o] = Mn;
        }
        __syncthreads();
    }
#pragma unroll
    for (int ob = 0; ob < 2; ++ob)
#pragma unroll
        for (int c = 0; c < 4; ++c) {
            float v = ssum[ob][c], v2 = ssq[ob][c];
#pragma unroll
            for (int off = 1; off < 16; off <<= 1) {
                v  += __shfl_xor(v,  off);
                v2 += __shfl_xor(v2, off);
            }
            if (m == 0) {
                int o = wid*32 + ob*16 + q*4 + c;
                atomicAdd(&gsum2[o], v);
                atomicAdd(&gsumsq2[o], v2);
            }
        }
}

// ---------------- epilogue: bn2+relu on max/min, transpose to (B,C,N) ----------------
__global__ void __launch_bounds__(256) k_epilogue(const float* __restrict__ wsmax,
                                                  const float* __restrict__ wsmin,
                                                  const float* __restrict__ ab2,
                                                  float* __restrict__ out) {
    __shared__ float t[128*65];
    int b = blockIdx.y;
    int n0 = blockIdx.x * 64;
    int tid = threadIdx.x;
#pragma unroll
    for (int i = 0; i < 32; ++i) {
        int idx = i*256 + tid;
        int nl = idx >> 7, o = idx & 127;
        int n = n0 + nl;
        float v = 0.f;
        if (n < NN) {
            float a = ab2[o], cc = ab2[CC + o];
            size_t p = (size_t)b*NN + n;
            float z = (a >= 0.f) ? wsmax[p*CC + o] : wsmin[p*CC + o];
            v = fmaf(a, z, cc);
            v = v > 0.f ? v : 0.f;
        }
        t[o*65 + nl] = v;
    }
    __syncthreads();
#pragma unroll
    for (int i = 0; i < 32; ++i) {
        int idx = i*256 + tid;
        int o = idx >> 6, nl = idx & 63;
        int n = n0 + nl;
        if (n < NN) out[((size_t)b*CC + o)*NN + n] = t[o*65 + nl];
    }
}

extern "C" void kernel_launch(void* const* d_in, const int* in_sizes, int n_in,
                              void* d_out, int out_size, void* d_ws, size_t ws_size,
                              hipStream_t stream) {
    const float* x      = (const float*)d_in[0];
    const float* coords = (const float*)d_in[1];
    const float* w1     = (const float*)d_in[2];
    const float* g1     = (const float*)d_in[3];
    const float* b1     = (const float*)d_in[4];
    const float* w2     = (const float*)d_in[5];
    const float* g2     = (const float*)d_in[6];
    const float* b2     = (const float*)d_in[7];
    float* out = (float*)d_out;

    char* ws = (char*)d_ws;
    size_t off = 0;
    int* knn_idx = (int*)(ws + off);   off += (size_t)ROWS * sizeof(int);        // 3.32 MB
    float* stats = (float*)(ws + off); off += 1024 * sizeof(float);
    float* gsum1 = stats,       *gsq1 = stats + 128;
    float* gsum2 = stats + 256, *gsq2 = stats + 384;
    float* ab1   = stats + 512;
    float* ab2   = stats + 768;
    __half* feats = (__half*)(ws + off); off += (size_t)BB*NN*DD * sizeof(__half); // 3.32 MB
    __half* w1h   = (__half*)(ws + off); off += CC*CC * sizeof(__half);
    __half* w2h   = (__half*)(ws + off); off += CC*CC * sizeof(__half);
    float* wsmax = (float*)(ws + off);  off += (size_t)PAIRS*CC * sizeof(float);  // 13.3 MB
    float* wsmin = (float*)(ws + off);  off += (size_t)PAIRS*CC * sizeof(float);  // 13.3 MB
    (void)ws_size; (void)in_sizes; (void)n_in; (void)out_size;

    hipMemsetAsync(stats, 0, 512 * sizeof(float), stream);

    dim3 gT((NN + 63)/64, BB);
    k_prep_feats<<<gT, 256, 0, stream>>>(x, feats);
    k_convert_w<<<64, 256, 0, stream>>>(w1, w2, w1h, w2h);
    k_knn<<<PAIRS, 64, 0, stream>>>(coords, knn_idx);
    k_mm1_mfma<<<GRID_MM, 256, 0, stream>>>(feats, knn_idx, w1h, gsum1, gsq1);
    k_finalize<<<1, CC, 0, stream>>>(gsum1, gsq1, g1, b1, ab1);
    k_fused_mfma<<<GRID_MM, 256, 0, stream>>>(feats, knn_idx, w1h, w2h, ab1,
                                              gsum2, gsq2, wsmax, wsmin);
    k_finalize<<<1, CC, 0, stream>>>(gsum2, gsq2, g2, b2, ab2);
    dim3 gE((NN + 63)/64, BB);
    k_epilogue<<<gE, 256, 0, stream>>>(wsmax, wsmin, ab2, out);
}

// Round 3
// 613.755 us; speedup vs baseline: 3.2168x; 1.4624x over previous
//
#include <hip/hip_runtime.h>
#include <hip/hip_fp16.h>
#include <stdint.h>

#define BB 16
#define NN 1620
#define DD 64
#define CC 128
#define KK 32
#define EPSV 1e-5f
#define PAIRS (BB*NN)            // 25920
#define ROWS  (PAIRS*KK)         // 829440
#define TILES (PAIRS/2)          // 12960 tiles of 64 rows
#define TPB_TILES 8
#define GRID_MM (TILES/TPB_TILES) // 1620
#define NCHUNK 26                // ceil(1620/64)

typedef _Float16 half8 __attribute__((ext_vector_type(8)));
typedef float f32x4 __attribute__((ext_vector_type(4)));

__device__ __forceinline__ float relu_(float v){ return v > 0.f ? v : 0.f; }

union H2U { __half2 h; unsigned u; };

// ---------------- x (B,D,N) fp32 -> feats (B,N,D) fp16 ----------------
__global__ void __launch_bounds__(256) k_prep_feats(const float* __restrict__ x,
                                                    __half* __restrict__ feats) {
    __shared__ float t[64*65];
    int b = blockIdx.y;
    int n0 = blockIdx.x * 64;
    int tid = threadIdx.x;
#pragma unroll
    for (int i = 0; i < 16; ++i) {
        int idx = i*256 + tid;
        int d = idx >> 6, nl = idx & 63;
        int n = n0 + nl;
        float v = 0.f;
        if (n < NN) v = x[((size_t)b*DD + d)*NN + n];
        t[d*65 + nl] = v;
    }
    __syncthreads();
#pragma unroll
    for (int i = 0; i < 8; ++i) {
        int idx = i*256 + tid;            // 64 nl x 32 d-pairs
        int nl = idx >> 5, dp = idx & 31;
        int n = n0 + nl;
        if (n < NN) {
            __half2 h = __floats2half2_rn(t[(dp*2)*65 + nl], t[(dp*2+1)*65 + nl]);
            *(__half2*)(feats + ((size_t)b*NN + n)*DD + dp*2) = h;
        }
    }
}

// ---------------- w fp32 -> fp16 (same [o][c] layout) ----------------
__global__ void k_convert_w(const float* __restrict__ w1, const float* __restrict__ w2,
                            __half* __restrict__ w1h, __half* __restrict__ w2h) {
    int i = blockIdx.x*256 + threadIdx.x;   // 64 blocks * 256 = 16384
    w1h[i] = __float2half(w1[i]);
    w2h[i] = __float2half(w2[i]);
}

// ---------------- KNN: one wave per query, radix-histogram rank selection ----------------
__global__ void __launch_bounds__(64) k_knn(const float* __restrict__ coords,
                                            int* __restrict__ idx_out) {
#pragma clang fp contract(off)
    __shared__ int hist[256];
    __shared__ unsigned bcast[2];   // [0]=bucket, [1]=count below bucket
    int p = blockIdx.x;
    int b = p / NN, n = p - b*NN;
    int lane = threadIdx.x;
    const float* cb = coords + (size_t)b*NN*3;
    float qx = cb[n*3+0], qy = cb[n*3+1], qz = cb[n*3+2];
    float sqn = (qx*qx + qy*qy) + qz*qz;

    // distances -> monotone uint keys, in registers
    unsigned key[NCHUNK];
#pragma unroll
    for (int i = 0; i < NCHUNK; ++i) {
        int m = lane + i*64;
        unsigned u = 0xFFFFFFFFu;      // sentinel for m >= NN (never selected)
        if (m < NN) {
            float cx = cb[m*3+0], cy = cb[m*3+1], cz = cb[m*3+2];
            float sqm = (cx*cx + cy*cy) + cz*cz;
            float dot = (qx*cx + qy*cy) + qz*cz;
            float d = (sqn + sqm) - 2.0f*dot;
            unsigned t = __float_as_uint(d);
            u = (t & 0x80000000u) ? ~t : (t | 0x80000000u);
        }
        key[i] = u;
    }

    // ---- pass A: histogram on key[31:24], find bucket of 32nd smallest ----
#pragma unroll
    for (int i = 0; i < 4; ++i) hist[lane + i*64] = 0;
    __syncthreads();
#pragma unroll
    for (int i = 0; i < NCHUNK; ++i) {
        int m = lane + i*64;
        if (m < NN) atomicAdd(&hist[key[i] >> 24], 1);
    }
    __syncthreads();
    {
        int v0 = hist[lane*4+0], v1 = hist[lane*4+1], v2 = hist[lane*4+2], v3 = hist[lane*4+3];
        int c1 = v0+v1, c2 = c1+v2, c3 = c2+v3;
        int inc = c3;
#pragma unroll
        for (int off = 1; off < 64; off <<= 1) {
            int t = __shfl_up(inc, off);
            if (lane >= off) inc += t;
        }
        int base = inc - c3;   // exclusive prefix over 4-bucket groups
        if (base < KK) {
            int u0 = base+v0, u1 = base+c1, u2 = base+c2, u3 = base+c3;
            if      (u0 >= KK) { bcast[0] = lane*4+0; bcast[1] = base; }
            else if (u1 >= KK) { bcast[0] = lane*4+1; bcast[1] = u0; }
            else if (u2 >= KK) { bcast[0] = lane*4+2; bcast[1] = u1; }
            else if (u3 >= KK) { bcast[0] = lane*4+3; bcast[1] = u2; }
        }
    }
    __syncthreads();
    unsigned BA = bcast[0];
    int rA = KK - (int)bcast[1];       // rank within bucket BA, 1..32
    __syncthreads();

    // ---- pass B: histogram on key[23:16] within bucket BA ----
#pragma unroll
    for (int i = 0; i < 4; ++i) hist[lane + i*64] = 0;
    __syncthreads();
#pragma unroll
    for (int i = 0; i < NCHUNK; ++i) {
        int m = lane + i*64;
        if (m < NN && (key[i] >> 24) == BA) atomicAdd(&hist[(key[i] >> 16) & 255], 1);
    }
    __syncthreads();
    {
        int v0 = hist[lane*4+0], v1 = hist[lane*4+1], v2 = hist[lane*4+2], v3 = hist[lane*4+3];
        int c1 = v0+v1, c2 = c1+v2, c3 = c2+v3;
        int inc = c3;
#pragma unroll
        for (int off = 1; off < 64; off <<= 1) {
            int t = __shfl_up(inc, off);
            if (lane >= off) inc += t;
        }
        int base = inc - c3;
        if (base < rA) {
            int u0 = base+v0, u1 = base+c1, u2 = base+c2, u3 = base+c3;
            if      (u0 >= rA) { bcast[0] = lane*4+0; bcast[1] = base; }
            else if (u1 >= rA) { bcast[0] = lane*4+1; bcast[1] = u0; }
            else if (u2 >= rA) { bcast[0] = lane*4+2; bcast[1] = u1; }
            else if (u3 >= rA) { bcast[0] = lane*4+3; bcast[1] = u2; }
        }
    }
    __syncthreads();
    unsigned prefix16 = (BA << 8) | bcast[0];
    int r = rA - (int)bcast[1];        // rank within 16-bit prefix group, >=1

    // ---- extract exact 32nd (key, m) pair: r rounds of wave-min over prefix-matched ----
    unsigned long long fl = 0;
    for (int round = 0; round < r; ++round) {
        unsigned long long best = ~0ull;
#pragma unroll
        for (int i = 0; i < NCHUNK; ++i) {
            if ((key[i] >> 16) == prefix16) {
                unsigned long long v = ((unsigned long long)key[i] << 32) | (unsigned)(lane + i*64);
                if (v > fl && v < best) best = v;
            }
        }
#pragma unroll
        for (int off = 32; off; off >>= 1) {
            unsigned long long o = __shfl_xor(best, off, 64);
            if (o < best) best = o;
        }
        fl = best;
    }
    unsigned kstar = (unsigned)(fl >> 32);
    unsigned mstar = (unsigned)fl;

    // ---- collect: all (key,m) lexicographically <= (kstar, mstar); ballot positions ----
    int cnt = 0;
    unsigned long long mylow = (1ull << lane) - 1ull;
#pragma unroll
    for (int i = 0; i < NCHUNK; ++i) {
        unsigned m = lane + i*64;
        bool sel = (key[i] < kstar) || (key[i] == kstar && m <= mstar);
        unsigned long long bal = __ballot(sel);
        if (sel) {
            int pos = cnt + __popcll(bal & mylow);
            idx_out[p*KK + pos] = (int)m;
        }
        cnt += __popcll(bal);
    }
}

// Stage one 64-row nf tile into LDS in MFMA B-fragment chunk order.
__device__ __forceinline__ void stage_tile(const __half* __restrict__ feats,
                                           const int* __restrict__ knn_idx,
                                           int tile, int tid,
                                           __half* nf, int* rowb, int* ctrb) {
    if (tid < 64) {
        int r = tid;
        int p = tile*2 + (r >> 5);
        int nb = knn_idx[p*KK + (r & 31)];
        int b = p / NN;
        rowb[r] = (b*NN + nb)*DD;
        ctrb[r] = p*DD;
    }
    __syncthreads();
#pragma unroll
    for (int i = 0; i < 4; ++i) {
        int C = i*256 + tid;
        int rr = ((C >> 8) << 4) | (C & 15);
        int k  = (((C >> 6) & 3) << 5) | (((C >> 4) & 3) << 3);
        union { uint4 u; __half2 h[4]; } A, Cc, R;
        if (k < DD) {
            A.u  = *(const uint4*)(feats + rowb[rr] + k);
            Cc.u = *(const uint4*)(feats + ctrb[rr] + k);
#pragma unroll
            for (int j = 0; j < 4; ++j) R.h[j] = __hsub2(A.h[j], Cc.h[j]);
        } else {
            R.u = *(const uint4*)(feats + ctrb[rr] + (k - DD));
        }
        *(uint4*)(nf + C*8) = R.u;
    }
}

// ---------------- pass 1: mm1 (MFMA) + stats1 ----------------
__global__ void __launch_bounds__(256) k_mm1_mfma(const __half* __restrict__ feats,
                                                  const int* __restrict__ knn_idx,
                                                  const __half* __restrict__ w1h,
                                                  float* __restrict__ gsum,
                                                  float* __restrict__ gsumsq) {
    __shared__ __align__(16) char smem[16384 + 512];
    __half* nf = (__half*)smem;
    int* rowb = (int*)(smem + 16384);
    int* ctrb = (int*)(smem + 16384 + 256);
    int tid = threadIdx.x;
    int lane = tid & 63, wid = tid >> 6;
    int m = lane & 15, q = lane >> 4;

    half8 w1f[2][4];
#pragma unroll
    for (int ob = 0; ob < 2; ++ob)
#pragma unroll
        for (int t = 0; t < 4; ++t)
            w1f[ob][t] = *(const half8*)(w1h + (wid*32 + ob*16 + m)*CC + t*32 + q*8);

    f32x4 zero4 = {0.f, 0.f, 0.f, 0.f};
    f32x4 ssum[2] = {zero4, zero4}, ssq[2] = {zero4, zero4};

    for (int it = 0; it < TPB_TILES; ++it) {
        int tile = blockIdx.x * TPB_TILES + it;
        stage_tile(feats, knn_idx, tile, tid, nf, rowb, ctrb);
        __syncthreads();

        f32x4 acc[2][4];
#pragma unroll
        for (int ob = 0; ob < 2; ++ob)
#pragma unroll
            for (int rbk = 0; rbk < 4; ++rbk) acc[ob][rbk] = zero4;

#pragma unroll
        for (int t = 0; t < 4; ++t)
#pragma unroll
            for (int rbk = 0; rbk < 4; ++rbk) {
                half8 bfr = *(const half8*)(nf + ((rbk*4 + t)*64 + lane)*8);
                acc[0][rbk] = __builtin_amdgcn_mfma_f32_16x16x32_f16(w1f[0][t], bfr, acc[0][rbk], 0, 0, 0);
                acc[1][rbk] = __builtin_amdgcn_mfma_f32_16x16x32_f16(w1f[1][t], bfr, acc[1][rbk], 0, 0, 0);
            }
#pragma unroll
        for (int ob = 0; ob < 2; ++ob)
#pragma unroll
            for (int rbk = 0; rbk < 4; ++rbk) {
                ssum[ob] += acc[ob][rbk];
                ssq[ob]  += acc[ob][rbk]*acc[ob][rbk];
            }
        __syncthreads();
    }
#pragma unroll
    for (int ob = 0; ob < 2; ++ob)
#pragma unroll
        for (int c = 0; c < 4; ++c) {
            float v = ssum[ob][c], v2 = ssq[ob][c];
#pragma unroll
            for (int off = 1; off < 16; off <<= 1) {
                v  += __shfl_xor(v,  off);
                v2 += __shfl_xor(v2, off);
            }
            if (m == 0) {
                int o = wid*32 + ob*16 + q*4 + c;
                atomicAdd(&gsum[o], v);
                atomicAdd(&gsumsq[o], v2);
            }
        }
}

// ---------------- finalize bn params ----------------
__global__ void k_finalize(const float* __restrict__ gsum, const float* __restrict__ gsumsq,
                           const float* __restrict__ g, const float* __restrict__ bb,
                           float* __restrict__ ab) {
    int o = threadIdx.x;
    float cnt = (float)ROWS;
    float mean = gsum[o] / cnt;
    float var = gsumsq[o] / cnt - mean*mean;
    float a = g[o] * rsqrtf(var + EPSV);
    ab[o] = a;
    ab[CC + o] = bb[o] - mean*a;
}

// ---------------- pass 2: mm1 + bn1relu + mm2 + stats2 + per-pair max/min ----------------
__global__ void __launch_bounds__(256) k_fused_mfma(const __half* __restrict__ feats,
                                                    const int* __restrict__ knn_idx,
                                                    const __half* __restrict__ w1h,
                                                    const __half* __restrict__ w2h,
                                                    const float* __restrict__ ab1,
                                                    float* __restrict__ gsum2,
                                                    float* __restrict__ gsumsq2,
                                                    float* __restrict__ wsmax,
                                                    float* __restrict__ wsmin) {
    __shared__ __align__(16) char smem[34304];
    __half* nf   = (__half*)smem;             // 16384 B chunk-order nf
    __half* y1s  = (__half*)(smem + 16384);   // 16384 B swizzled row-major y1
    float* redmx = (float*)smem;              // aliases nf/y1s after sync
    float* redmn = (float*)(smem + 16896);
    int* rowb = (int*)(smem + 33792);
    int* ctrb = (int*)(smem + 34048);
    int tid = threadIdx.x;
    int lane = tid & 63, wid = tid >> 6;
    int m = lane & 15, q = lane >> 4;

    half8 w1f[2][4], w2f[2][4];
#pragma unroll
    for (int ob = 0; ob < 2; ++ob)
#pragma unroll
        for (int t = 0; t < 4; ++t) {
            int o = wid*32 + ob*16 + m;
            w1f[ob][t] = *(const half8*)(w1h + o*CC + t*32 + q*8);
            w2f[ob][t] = *(const half8*)(w2h + o*CC + t*32 + q*8);
        }
    f32x4 a1v[2], c1v[2];
#pragma unroll
    for (int ob = 0; ob < 2; ++ob) {
        a1v[ob] = *(const f32x4*)(ab1 + wid*32 + ob*16 + q*4);
        c1v[ob] = *(const f32x4*)(ab1 + CC + wid*32 + ob*16 + q*4);
    }
    f32x4 zero4 = {0.f, 0.f, 0.f, 0.f};
    f32x4 ssum[2] = {zero4, zero4}, ssq[2] = {zero4, zero4};

    for (int it = 0; it < TPB_TILES; ++it) {
        int tile = blockIdx.x * TPB_TILES + it;
        stage_tile(feats, knn_idx, tile, tid, nf, rowb, ctrb);
        __syncthreads();

        f32x4 acc[2][4];
#pragma unroll
        for (int ob = 0; ob < 2; ++ob)
#pragma unroll
            for (int rbk = 0; rbk < 4; ++rbk) acc[ob][rbk] = zero4;

        // mm1: z1^T = w1 . nf^T
#pragma unroll
        for (int t = 0; t < 4; ++t)
#pragma unroll
            for (int rbk = 0; rbk < 4; ++rbk) {
                half8 bfr = *(const half8*)(nf + ((rbk*4 + t)*64 + lane)*8);
                acc[0][rbk] = __builtin_amdgcn_mfma_f32_16x16x32_f16(w1f[0][t], bfr, acc[0][rbk], 0, 0, 0);
                acc[1][rbk] = __builtin_amdgcn_mfma_f32_16x16x32_f16(w1f[1][t], bfr, acc[1][rbk], 0, 0, 0);
            }
        // bn1 + relu, write y1 (swizzled chunks: ch' = ch ^ (row&15))
#pragma unroll
        for (int ob = 0; ob < 2; ++ob)
#pragma unroll
            for (int rbk = 0; rbk < 4; ++rbk) {
                f32x4 z = acc[ob][rbk];
                float y0 = relu_(fmaf(a1v[ob][0], z[0], c1v[ob][0]));
                float y1 = relu_(fmaf(a1v[ob][1], z[1], c1v[ob][1]));
                float y2 = relu_(fmaf(a1v[ob][2], z[2], c1v[ob][2]));
                float y3 = relu_(fmaf(a1v[ob][3], z[3], c1v[ob][3]));
                H2U p0, p1;
                p0.h = __floats2half2_rn(y0, y1);
                p1.h = __floats2half2_rn(y2, y3);
                int row = rbk*16 + m;
                int ch = (wid*4 + ob*2 + (q >> 1)) ^ m;
                uint2 v; v.x = p0.u; v.y = p1.u;
                *(uint2*)(y1s + row*CC + ch*8 + (q & 1)*4) = v;
            }
        __syncthreads();

        // mm2: z2^T = w2 . y1^T
#pragma unroll
        for (int ob = 0; ob < 2; ++ob)
#pragma unroll
            for (int rbk = 0; rbk < 4; ++rbk) acc[ob][rbk] = zero4;
#pragma unroll
        for (int t = 0; t < 4; ++t)
#pragma unroll
            for (int rbk = 0; rbk < 4; ++rbk) {
                int row = rbk*16 + m;
                int ch = (t*4 + q) ^ m;
                half8 bfr = *(const half8*)(y1s + row*CC + ch*8);
                acc[0][rbk] = __builtin_amdgcn_mfma_f32_16x16x32_f16(w2f[0][t], bfr, acc[0][rbk], 0, 0, 0);
                acc[1][rbk] = __builtin_amdgcn_mfma_f32_16x16x32_f16(w2f[1][t], bfr, acc[1][rbk], 0, 0, 0);
            }
#pragma unroll
        for (int ob = 0; ob < 2; ++ob)
#pragma unroll
            for (int rbk = 0; rbk < 4; ++rbk) {
                ssum[ob] += acc[ob][rbk];
                ssq[ob]  += acc[ob][rbk]*acc[ob][rbk];
            }
        __syncthreads();   // all y1 reads done before aliasing smem as redbuf

#pragma unroll
        for (int ob = 0; ob < 2; ++ob)
#pragma unroll
            for (int pr = 0; pr < 2; ++pr) {
                f32x4 a0 = acc[ob][pr*2], a1 = acc[ob][pr*2 + 1];
                f32x4 vmx, vmn;
#pragma unroll
                for (int c = 0; c < 4; ++c) {
                    vmx[c] = fmaxf(a0[c], a1[c]);
                    vmn[c] = fminf(a0[c], a1[c]);
                }
                int o0 = wid*32 + ob*16 + q*4;
                *(f32x4*)(redmx + (pr*16 + m)*132 + o0) = vmx;
                *(f32x4*)(redmn + (pr*16 + m)*132 + o0) = vmn;
            }
        __syncthreads();
        {
            int pr = tid >> 7, o = tid & 127;
            float M  = redmx[(pr*16)*132 + o];
            float Mn = redmn[(pr*16)*132 + o];
#pragma unroll
            for (int mm = 1; mm < 16; ++mm) {
                M  = fmaxf(M,  redmx[(pr*16 + mm)*132 + o]);
                Mn = fminf(Mn, redmn[(pr*16 + mm)*132 + o]);
            }
            int p = tile*2 + pr;
            wsmax[(size_t)p*CC + o] = M;
            wsmin[(size_t)p*CC + o] = Mn;
        }
        __syncthreads();
    }
#pragma unroll
    for (int ob = 0; ob < 2; ++ob)
#pragma unroll
        for (int c = 0; c < 4; ++c) {
            float v = ssum[ob][c], v2 = ssq[ob][c];
#pragma unroll
            for (int off = 1; off < 16; off <<= 1) {
                v  += __shfl_xor(v,  off);
                v2 += __shfl_xor(v2, off);
            }
            if (m == 0) {
                int o = wid*32 + ob*16 + q*4 + c;
                atomicAdd(&gsum2[o], v);
                atomicAdd(&gsumsq2[o], v2);
            }
        }
}

// ---------------- epilogue: bn2+relu on max/min, transpose to (B,C,N) ----------------
__global__ void __launch_bounds__(256) k_epilogue(const float* __restrict__ wsmax,
                                                  const float* __restrict__ wsmin,
                                                  const float* __restrict__ ab2,
                                                  float* __restrict__ out) {
    __shared__ float t[128*65];
    int b = blockIdx.y;
    int n0 = blockIdx.x * 64;
    int tid = threadIdx.x;
#pragma unroll
    for (int i = 0; i < 32; ++i) {
        int idx = i*256 + tid;
        int nl = idx >> 7, o = idx & 127;
        int n = n0 + nl;
        float v = 0.f;
        if (n < NN) {
            float a = ab2[o], cc = ab2[CC + o];
            size_t p = (size_t)b*NN + n;
            float z = (a >= 0.f) ? wsmax[p*CC + o] : wsmin[p*CC + o];
            v = fmaf(a, z, cc);
            v = v > 0.f ? v : 0.f;
        }
        t[o*65 + nl] = v;
    }
    __syncthreads();
#pragma unroll
    for (int i = 0; i < 32; ++i) {
        int idx = i*256 + tid;
        int o = idx >> 6, nl = idx & 63;
        int n = n0 + nl;
        if (n < NN) out[((size_t)b*CC + o)*NN + n] = t[o*65 + nl];
    }
}

extern "C" void kernel_launch(void* const* d_in, const int* in_sizes, int n_in,
                              void* d_out, int out_size, void* d_ws, size_t ws_size,
                              hipStream_t stream) {
    const float* x      = (const float*)d_in[0];
    const float* coords = (const float*)d_in[1];
    const float* w1     = (const float*)d_in[2];
    const float* g1     = (const float*)d_in[3];
    const float* b1     = (const float*)d_in[4];
    const float* w2     = (const float*)d_in[5];
    const float* g2     = (const float*)d_in[6];
    const float* b2     = (const float*)d_in[7];
    float* out = (float*)d_out;

    char* ws = (char*)d_ws;
    size_t off = 0;
    int* knn_idx = (int*)(ws + off);   off += (size_t)ROWS * sizeof(int);        // 3.32 MB
    float* stats = (float*)(ws + off); off += 1024 * sizeof(float);
    float* gsum1 = stats,       *gsq1 = stats + 128;
    float* gsum2 = stats + 256, *gsq2 = stats + 384;
    float* ab1   = stats + 512;
    float* ab2   = stats + 768;
    __half* feats = (__half*)(ws + off); off += (size_t)BB*NN*DD * sizeof(__half); // 3.32 MB
    __half* w1h   = (__half*)(ws + off); off += CC*CC * sizeof(__half);
    __half* w2h   = (__half*)(ws + off); off += CC*CC * sizeof(__half);
    float* wsmax = (float*)(ws + off);  off += (size_t)PAIRS*CC * sizeof(float);  // 13.3 MB
    float* wsmin = (float*)(ws + off);  off += (size_t)PAIRS*CC * sizeof(float);  // 13.3 MB
    (void)ws_size; (void)in_sizes; (void)n_in; (void)out_size;

    hipMemsetAsync(stats, 0, 512 * sizeof(float), stream);

    dim3 gT((NN + 63)/64, BB);
    k_prep_feats<<<gT, 256, 0, stream>>>(x, feats);
    k_convert_w<<<64, 256, 0, stream>>>(w1, w2, w1h, w2h);
    k_knn<<<PAIRS, 64, 0, stream>>>(coords, knn_idx);
    k_mm1_mfma<<<GRID_MM, 256, 0, stream>>>(feats, knn_idx, w1h, gsum1, gsq1);
    k_finalize<<<1, CC, 0, stream>>>(gsum1, gsq1, g1, b1, ab1);
    k_fused_mfma<<<GRID_MM, 256, 0, stream>>>(feats, knn_idx, w1h, w2h, ab1,
                                              gsum2, gsq2, wsmax, wsmin);
    k_finalize<<<1, CC, 0, stream>>>(gsum2, gsq2, g2, b2, ab2);
    dim3 gE((NN + 63)/64, BB);
    k_epilogue<<<gE, 256, 0, stream>>>(wsmax, wsmin, ab2, out);
}